// Round 15
// baseline (56.348 us; speedup 1.0000x reference)
//
#include <hip/hip_runtime.h>
#include <math.h>

// Problem constants
#define B_SZ   8192
#define D_IN   512
#define M0_N   128
#define M1_N   128
#define K_TOP  8
#define H_DIM  128
#define ROWS   16          // batch rows per block
#define XP     520         // LDS x-tile row pitch (floats)
#define FLAG   256         // ws int index of the routing-done flag

// ws layout (ints), written by block 0 (pre-resolved, positional):
//   [0..1]     m1[2]      : selected layer-1 modules
//   [16..31]   m0[16]     : layer-0 module for slot s = j*8+k
//   [32..159]  cols[s*8+k]: top-8 input dims of x for slot s
//   [256]      flag       : 0 -> 1 when routing published (memset 0 per call)

// ---------------------------------------------------------------------------
// Wave-parallel iterative top-k into lane-0 registers.
// jax.lax.top_k semantics: descending value, ties -> lowest index.
template<int NCH, int K>
__device__ __forceinline__ void wave_topk_reg(const float* __restrict__ base,
                                              int stride, int lane,
                                              int (&out)[K]) {
  float v[NCH];
#pragma unroll
  for (int t = 0; t < NCH; ++t) v[t] = base[(t * 64 + lane) * stride];
#pragma unroll
  for (int r = 0; r < K; ++r) {
    float bv = -INFINITY;
    int bd = 0x7fffffff;
#pragma unroll
    for (int t = 0; t < NCH; ++t) {
      if (v[t] > bv) { bv = v[t]; bd = t * 64 + lane; }
    }
#pragma unroll
    for (int m = 1; m < 64; m <<= 1) {
      float ov = __shfl_xor(bv, m, 64);
      int   od = __shfl_xor(bd, m, 64);
      if (ov > bv || (ov == bv && od < bd)) { bv = ov; bd = od; }
    }
    if (lane == 0) out[r] = bd;
    if ((bd & 63) == lane) {
      const int tw = bd >> 6;
#pragma unroll
      for (int tt = 0; tt < NCH; ++tt)
        if (tt == tw) v[tt] = -INFINITY;
    }
  }
}

// ---------------------------------------------------------------------------
// 16-lane sum reduce entirely on the VALU pipe via DPP (no DS ops).
__device__ __forceinline__ float dpp_add16(float p) {
  int t;
  t = __builtin_amdgcn_update_dpp(0, __float_as_int(p), 0xB1, 0xF, 0xF, true);
  p += __int_as_float(t);
  t = __builtin_amdgcn_update_dpp(0, __float_as_int(p), 0x4E, 0xF, 0xF, true);
  p += __int_as_float(t);
  t = __builtin_amdgcn_update_dpp(0, __float_as_int(p), 0x124, 0xF, 0xF, true);
  p += __int_as_float(t);
  t = __builtin_amdgcn_update_dpp(0, __float_as_int(p), 0x128, 0xF, 0xF, true);
  p += __int_as_float(t);
  return p;
}

// Per-thread 8-hidden-unit MLP slice + DPP reduce. Lane (g=lane&15, rq).
__device__ __forceinline__ float slice8(const float4* w1a, const float4* w1b,
                                        const float4& b1a, const float4& b1b,
                                        const float4& w2a, const float4& w2b,
                                        const float* xv) {
  float4 h0 = b1a, h1 = b1b;
#pragma unroll
  for (int k = 0; k < 8; ++k) {
    h0.x = fmaf(xv[k], w1a[k].x, h0.x);
    h0.y = fmaf(xv[k], w1a[k].y, h0.y);
    h0.z = fmaf(xv[k], w1a[k].z, h0.z);
    h0.w = fmaf(xv[k], w1a[k].w, h0.w);
    h1.x = fmaf(xv[k], w1b[k].x, h1.x);
    h1.y = fmaf(xv[k], w1b[k].y, h1.y);
    h1.z = fmaf(xv[k], w1b[k].z, h1.z);
    h1.w = fmaf(xv[k], w1b[k].w, h1.w);
  }
  float pa = 0.f, pb = 0.f;
  pa = fmaf(fmaxf(h0.x, 0.f), w2a.x, pa);
  pa = fmaf(fmaxf(h0.y, 0.f), w2a.y, pa);
  pa = fmaf(fmaxf(h0.z, 0.f), w2a.z, pa);
  pa = fmaf(fmaxf(h0.w, 0.f), w2a.w, pa);
  pb = fmaf(fmaxf(h1.x, 0.f), w2b.x, pb);
  pb = fmaf(fmaxf(h1.y, 0.f), w2b.y, pb);
  pb = fmaf(fmaxf(h1.z, 0.f), w2b.z, pb);
  pb = fmaf(fmaxf(h1.w, 0.f), w2b.w, pb);
  return dpp_add16(pa + pb);
}

// ---------------------------------------------------------------------------
// Single dispatch; block 0 is the SOLE routing producer (one flag store,
// zero atomic RMWs, zero cache flushes):
//  block 0   : 3-stage routing chain (emb_out -> emb1 -> emb0) on its 4 waves,
//              publish 146 pre-resolved ints (relaxed agent stores), barrier
//              (drains vmcnt -> stores acked at coherence point), ONE relaxed
//              flag store; then stages its x-tile and computes as usual.
//  blocks >0 : stage x-tile (HBM-heavy, overlaps producer's routing), park,
//              relaxed-poll flag with s_sleep backoff, one round of relaxed
//              loads (no dependent chain), then compute.
// Co-residency: 512 blocks == 2/CU capacity -> every block resident -> no
// deadlock regardless of dispatch order.
__global__ __launch_bounds__(256, 2)
void mono(const float* __restrict__ x,
          const int* __restrict__ task_id_p,
          const float* __restrict__ emb0,
          const float* __restrict__ emb1,
          const float* __restrict__ emb_out,
          const float* __restrict__ W1_0, const float* __restrict__ b1_0,
          const float* __restrict__ W2_0, const float* __restrict__ b2_0,
          const float* __restrict__ W1_1, const float* __restrict__ b1_1,
          const float* __restrict__ W2_1, const float* __restrict__ b2_1,
          int* __restrict__ ws, float* __restrict__ out) {
  __shared__ __align__(16) float xt[ROWS * XP];   // 33.3 KB x-tile
  __shared__ int   s_m1[2];
  __shared__ int   s_m0[16];
  __shared__ int   s_cols[128];
  __shared__ float tile[16 * 18];                 // layer-0 outputs [slot][row]

  const int tid  = threadIdx.x;
  const int b    = blockIdx.x;
  const int wid  = tid >> 6;
  const int lane = tid & 63;
  const int rowbase = b * ROWS;
  const bool producer = (b == 0);

  float4 xr[8];

  if (!producer) {
    // ---- consumers: issue coalesced x-tile loads immediately ----
#pragma unroll
    for (int i = 0; i < 8; ++i) {
      const int e = tid + i * 256;
      xr[i] = *(const float4*)(x + (size_t)(rowbase + (e >> 7)) * D_IN +
                               (e & 127) * 4);
    }
  } else {
    // ---- block 0: full routing chain, then publish ----
    const int task = task_id_p[0];
    // stage 1: emb_out top-2 (wave 0)
    if (wid == 0) {
      int o[2];
      wave_topk_reg<2, 2>(emb_out + task * M1_N, 1, lane, o);
      if (lane == 0) { s_m1[0] = o[0]; s_m1[1] = o[1]; }
    }
    __syncthreads();
    // stage 2: emb1 top-8 for the 2 selected modules (waves 0,1)
    if (wid < 2) {
      int o[8];
      wave_topk_reg<2, 8>(emb1 + (size_t)task * M0_N * M1_N + s_m1[wid],
                          M1_N, lane, o);
      if (lane == 0) {
#pragma unroll
        for (int r = 0; r < 8; ++r) s_m0[wid * 8 + r] = o[r];
      }
    }
    __syncthreads();
    // stage 3: emb0 top-8 for 16 slots, 4 per wave
#pragma unroll
    for (int si = 0; si < 4; ++si) {
      const int s = wid * 4 + si;
      int o[8];
      wave_topk_reg<8, 8>(emb0 + (size_t)task * D_IN * M0_N + s_m0[s],
                          M0_N, lane, o);
      if (lane == 0) {
#pragma unroll
        for (int r = 0; r < 8; ++r) s_cols[s * 8 + r] = o[r];
      }
    }
    __syncthreads();
    // publish pre-resolved routing (relaxed agent stores, distinct words)
    if (tid < 2)
      __hip_atomic_store(ws + tid, s_m1[tid], __ATOMIC_RELAXED,
                         __HIP_MEMORY_SCOPE_AGENT);
    if (tid >= 16 && tid < 32)
      __hip_atomic_store(ws + tid, s_m0[tid - 16], __ATOMIC_RELAXED,
                         __HIP_MEMORY_SCOPE_AGENT);
    if (tid >= 32 && tid < 160)
      __hip_atomic_store(ws + tid, s_cols[tid - 32], __ATOMIC_RELAXED,
                         __HIP_MEMORY_SCOPE_AGENT);
    __syncthreads();   // emits s_waitcnt vmcnt(0) per thread -> stores acked
    if (tid == 0)
      __hip_atomic_store(ws + FLAG, 1, __ATOMIC_RELAXED,
                         __HIP_MEMORY_SCOPE_AGENT);
    // now issue block 0's own x-tile loads
#pragma unroll
    for (int i = 0; i < 8; ++i) {
      const int e = tid + i * 256;
      xr[i] = *(const float4*)(x + (size_t)(rowbase + (e >> 7)) * D_IN +
                               (e & 127) * 4);
    }
  }

  // ---- park x tile in LDS ----
#pragma unroll
  for (int i = 0; i < 8; ++i) {
    const int e = tid + i * 256;
    *(float4*)(xt + (e >> 7) * XP + (e & 127) * 4) = xr[i];
  }

  // ---- consumers: wait for routing, then fetch it (one flat round) ----
  if (!producer) {
    if (tid == 0) {
      while (__hip_atomic_load(ws + FLAG, __ATOMIC_RELAXED,
                               __HIP_MEMORY_SCOPE_AGENT) != 1)
        __builtin_amdgcn_s_sleep(16);
    }
    __syncthreads();
    if (tid < 2)
      s_m1[tid] = __hip_atomic_load(ws + tid, __ATOMIC_RELAXED,
                                    __HIP_MEMORY_SCOPE_AGENT);
    if (tid >= 16 && tid < 32)
      s_m0[tid - 16] = __hip_atomic_load(ws + tid, __ATOMIC_RELAXED,
                                         __HIP_MEMORY_SCOPE_AGENT);
    if (tid >= 32 && tid < 160)
      s_cols[tid - 32] = __hip_atomic_load(ws + tid, __ATOMIC_RELAXED,
                                           __HIP_MEMORY_SCOPE_AGENT);
  }
  __syncthreads();

  const int g  = lane & 15;             // h-group: units 8g..8g+7
  const int rq = lane >> 4;             // row-in-group 0..3

  // ---- layer 0: wave w -> slots 4w..4w+3; 4 iters x 4 rows = 16 rows ----
#pragma unroll
  for (int si = 0; si < 4; ++si) {
    const int s  = wid * 4 + si;
    const int m0 = s_m0[s];
    const float4* w1p = (const float4*)(W1_0 + (size_t)m0 * (K_TOP * H_DIM));
    float4 w1a[8], w1b[8];
#pragma unroll
    for (int k = 0; k < 8; ++k) {
      w1a[k] = w1p[k * 32 + 2 * g];
      w1b[k] = w1p[k * 32 + 2 * g + 1];
    }
    const float4 b1a = ((const float4*)(b1_0 + m0 * H_DIM))[2 * g];
    const float4 b1b = ((const float4*)(b1_0 + m0 * H_DIM))[2 * g + 1];
    const float4 w2a = ((const float4*)(W2_0 + m0 * H_DIM))[2 * g];
    const float4 w2b = ((const float4*)(W2_0 + m0 * H_DIM))[2 * g + 1];
    const float  b2v = b2_0[m0];
    int cols[8];
#pragma unroll
    for (int k = 0; k < 8; ++k) cols[k] = s_cols[s * 8 + k];

#pragma unroll
    for (int it = 0; it < 4; ++it) {
      const int r = it * 4 + rq;
      const float* xrow = xt + r * XP;
      float xv[8];
#pragma unroll
      for (int k = 0; k < 8; ++k) xv[k] = xrow[cols[k]];
      const float p = slice8(w1a, w1b, b1a, b1b, w2a, w2b, xv);
      if (g == 0) tile[s * 18 + r] = p + b2v;
    }
  }
  __syncthreads();

  // ---- layer 1: wave w -> module j=w&1, row-half w>>1; + sigmoid ----
  {
    const int j  = wid & 1;
    const int rh = wid >> 1;
    const int m1 = s_m1[j];
    const float4* w1p = (const float4*)(W1_1 + (size_t)m1 * (K_TOP * H_DIM));
    float4 w1a[8], w1b[8];
#pragma unroll
    for (int k = 0; k < 8; ++k) {
      w1a[k] = w1p[k * 32 + 2 * g];
      w1b[k] = w1p[k * 32 + 2 * g + 1];
    }
    const float4 b1a = ((const float4*)(b1_1 + m1 * H_DIM))[2 * g];
    const float4 b1b = ((const float4*)(b1_1 + m1 * H_DIM))[2 * g + 1];
    const float4 w2a = ((const float4*)(W2_1 + m1 * H_DIM))[2 * g];
    const float4 w2b = ((const float4*)(W2_1 + m1 * H_DIM))[2 * g + 1];
    const float  b2v = b2_1[m1];

#pragma unroll
    for (int it = 0; it < 2; ++it) {
      const int r = rh * 8 + it * 4 + rq;
      float xv[8];
#pragma unroll
      for (int k = 0; k < 8; ++k) xv[k] = tile[(j * 8 + k) * 18 + r];
      const float p = slice8(w1a, w1b, b1a, b1b, w2a, w2b, xv);
      if (g == 0) {
        const float v = p + b2v;
        out[(size_t)(rowbase + r) * 2 + j] = 1.f / (1.f + __expf(-v));
      }
    }
  }
}

// ---------------------------------------------------------------------------
extern "C" void kernel_launch(void* const* d_in, const int* in_sizes, int n_in,
                              void* d_out, int out_size, void* d_ws, size_t ws_size,
                              hipStream_t stream) {
  const float* x       = (const float*)d_in[0];
  const int*   task_id = (const int*)  d_in[1];
  const float* emb0    = (const float*)d_in[2];
  const float* emb1    = (const float*)d_in[3];
  const float* emb_out = (const float*)d_in[4];
  const float* W1_0    = (const float*)d_in[5];
  const float* b1_0    = (const float*)d_in[6];
  const float* W2_0    = (const float*)d_in[7];
  const float* b2_0    = (const float*)d_in[8];
  const float* W1_1    = (const float*)d_in[9];
  const float* b1_1    = (const float*)d_in[10];
  const float* W2_1    = (const float*)d_in[11];
  const float* b2_1    = (const float*)d_in[12];

  int*   ws  = (int*)d_ws;
  float* out = (float*)d_out;

  // zero the flag (graph-legal async memset; deterministic per call)
  hipMemsetAsync((char*)d_ws + FLAG * sizeof(int), 0, sizeof(int), stream);

  mono<<<B_SZ / ROWS, 256, 0, stream>>>(x, task_id, emb0, emb1, emb_out,
                                        W1_0, b1_0, W2_0, b2_0,
                                        W1_1, b1_1, W2_1, b2_1, ws, out);
}

// Round 16
// 23.949 us; speedup vs baseline: 2.3529x; 2.3529x over previous
//
#include <hip/hip_runtime.h>
#include <math.h>

// Problem constants
#define B_SZ   8192
#define D_IN   512
#define M0_N   128
#define M1_N   128
#define K_TOP  8
#define H_DIM  128
#define ROWS   16          // batch rows per compute block
#define XP     520         // LDS x-tile row pitch (floats)

// ws layout (ints):
//   [0..1]       idx_out  (top-2 modules of emb_out)
//   [64..1087]   pre1[col*8+r] : top-8 of emb1[task][:,col], all 128 cols
//   [2048..3071] pre0[col*8+r] : top-8 of emb0[task][:,col], all 128 cols

// ---------------------------------------------------------------------------
// Wave-parallel iterative top-k, jax.lax.top_k semantics (descending value,
// ties -> lowest index). NCH*64 candidates; lane 0 writes out_idx.
template<int NCH>
__device__ __forceinline__ void wave_topk(const float* __restrict__ base,
                                          int stride, int k, int* out_idx,
                                          int lane) {
  float v[NCH];
#pragma unroll
  for (int t = 0; t < NCH; ++t) v[t] = base[(t * 64 + lane) * stride];
  for (int r = 0; r < k; ++r) {
    float bv = -INFINITY;
    int bd = 0x7fffffff;
#pragma unroll
    for (int t = 0; t < NCH; ++t) {
      if (v[t] > bv) { bv = v[t]; bd = t * 64 + lane; }
    }
#pragma unroll
    for (int m = 1; m < 64; m <<= 1) {
      float ov = __shfl_xor(bv, m, 64);
      int   od = __shfl_xor(bd, m, 64);
      if (ov > bv || (ov == bv && od < bd)) { bv = ov; bd = od; }
    }
    if (lane == 0) out_idx[r] = bd;
    if ((bd & 63) == lane) {
      const int tw = bd >> 6;
#pragma unroll
      for (int tt = 0; tt < NCH; ++tt)
        if (tt == tw) v[tt] = -INFINITY;
    }
  }
}

// ---------------------------------------------------------------------------
// Speculative routing: top-8 for ALL columns of emb1 and emb0, one column per
// wave (256 waves chip-wide). Block(0,0) wave 0 also does emb_out top-2.
__global__ __launch_bounds__(256)
void route_pre(const int* __restrict__ task_id_p,
               const float* __restrict__ emb0,
               const float* __restrict__ emb1,
               const float* __restrict__ emb_out,
               int* __restrict__ ws) {
  const int task = task_id_p[0];
  const int lane = threadIdx.x & 63;
  const int wid  = threadIdx.x >> 6;
  const int col  = blockIdx.x * 4 + wid;
  if (blockIdx.y == 0) {
    wave_topk<2>(emb1 + (size_t)task * M0_N * M1_N + col, M1_N, K_TOP,
                 ws + 64 + col * 8, lane);
    if (blockIdx.x == 0 && wid == 0)
      wave_topk<2>(emb_out + task * M1_N, 1, 2, ws, lane);
  } else {
    wave_topk<8>(emb0 + (size_t)task * D_IN * M0_N + col, M0_N, K_TOP,
                 ws + 2048 + col * 8, lane);
  }
}

// ---------------------------------------------------------------------------
// 16-lane sum reduce entirely on the VALU pipe via DPP (no DS ops).
__device__ __forceinline__ float dpp_add16(float p) {
  int t;
  t = __builtin_amdgcn_update_dpp(0, __float_as_int(p), 0xB1, 0xF, 0xF, true);
  p += __int_as_float(t);
  t = __builtin_amdgcn_update_dpp(0, __float_as_int(p), 0x4E, 0xF, 0xF, true);
  p += __int_as_float(t);
  t = __builtin_amdgcn_update_dpp(0, __float_as_int(p), 0x124, 0xF, 0xF, true);
  p += __int_as_float(t);
  t = __builtin_amdgcn_update_dpp(0, __float_as_int(p), 0x128, 0xF, 0xF, true);
  p += __int_as_float(t);
  return p;
}

// Per-thread 8-hidden-unit MLP slice + DPP reduce. Lane (g=lane&15, rq).
__device__ __forceinline__ float slice8(const float4* w1a, const float4* w1b,
                                        const float4& b1a, const float4& b1b,
                                        const float4& w2a, const float4& w2b,
                                        const float* xv) {
  float4 h0 = b1a, h1 = b1b;
#pragma unroll
  for (int k = 0; k < 8; ++k) {
    h0.x = fmaf(xv[k], w1a[k].x, h0.x);
    h0.y = fmaf(xv[k], w1a[k].y, h0.y);
    h0.z = fmaf(xv[k], w1a[k].z, h0.z);
    h0.w = fmaf(xv[k], w1a[k].w, h0.w);
    h1.x = fmaf(xv[k], w1b[k].x, h1.x);
    h1.y = fmaf(xv[k], w1b[k].y, h1.y);
    h1.z = fmaf(xv[k], w1b[k].z, h1.z);
    h1.w = fmaf(xv[k], w1b[k].w, h1.w);
  }
  float pa = 0.f, pb = 0.f;
  pa = fmaf(fmaxf(h0.x, 0.f), w2a.x, pa);
  pa = fmaf(fmaxf(h0.y, 0.f), w2a.y, pa);
  pa = fmaf(fmaxf(h0.z, 0.f), w2a.z, pa);
  pa = fmaf(fmaxf(h0.w, 0.f), w2a.w, pa);
  pb = fmaf(fmaxf(h1.x, 0.f), w2b.x, pb);
  pb = fmaf(fmaxf(h1.y, 0.f), w2b.y, pb);
  pb = fmaf(fmaxf(h1.z, 0.f), w2b.z, pb);
  pb = fmaf(fmaxf(h1.w, 0.f), w2b.w, pb);
  return dpp_add16(pa + pb);
}

// ---------------------------------------------------------------------------
// Fused compute. Fix vs R10: the x-tile staging uses global_load_lds DMA
// (zero VGPR staging -> nothing for the compiler to spill; R10's float4 xr[8]
// was silently spilled to scratch = 16.8 MB HBM write + read per call).
// Per wave: 8 chunks; chunk = wid*8+i (wave-uniform); each chunk is a
// contiguous 1 KB half-row of the LDS tile (dest = base + lane*16, per m104).
__global__ __launch_bounds__(256, 2)
void fused_compute(const float* __restrict__ x,
                   const float* __restrict__ W1_0, const float* __restrict__ b1_0,
                   const float* __restrict__ W2_0, const float* __restrict__ b2_0,
                   const float* __restrict__ W1_1, const float* __restrict__ b1_1,
                   const float* __restrict__ W2_1, const float* __restrict__ b2_1,
                   const int* __restrict__ ws, float* __restrict__ out) {
  __shared__ __align__(16) float xt[ROWS * XP];   // 33.3 KB x-tile
  __shared__ int   s_m1[2];
  __shared__ int   s_m0[16];
  __shared__ int   s_cols[128];
  __shared__ float tile[16 * 18];                 // layer-0 outputs [slot][row]

  const int tid  = threadIdx.x;
  const int wid  = tid >> 6;
  const int lane = tid & 63;
  const int rowbase = blockIdx.x * ROWS;

  // ---- stage x-tile via direct HBM->LDS DMA (no VGPRs, no spill) ----
#pragma unroll
  for (int i = 0; i < 8; ++i) {
    const int chunk = wid * 8 + i;      // wave-uniform, 0..31
    const int row   = chunk >> 1;       // 2 chunks per 512-float row
    const int half  = chunk & 1;
    const float* gsrc = x + (size_t)(rowbase + row) * D_IN + half * 256 +
                        lane * 4;
    float* ldst = xt + row * XP + half * 256;   // wave-uniform base
    __builtin_amdgcn_global_load_lds(
        (const __attribute__((address_space(1))) void*)gsrc,
        (__attribute__((address_space(3))) void*)ldst, 16, 0, 0);
  }

  // ---- routing resolution (L2 chain, overlaps the DMA drain) ----
  if (tid < 128) {
    const int slot = tid >> 3, k = tid & 7;
    const int m1 = ws[slot >> 3];
    const int m0 = ws[64 + m1 * 8 + (slot & 7)];
    if (k == 0) s_m0[slot] = m0;
    s_cols[tid] = ws[2048 + m0 * 8 + k];
    if (tid < 2) s_m1[tid] = ws[tid];
  }
  __syncthreads();                      // drains vmcnt -> DMA + LDS visible

  const int g  = lane & 15;             // h-group: units 8g..8g+7
  const int rq = lane >> 4;             // row-in-group 0..3

  // ---- layer 0: wave w -> slots 4w..4w+3; 4 iters x 4 rows = 16 rows ----
#pragma unroll
  for (int si = 0; si < 4; ++si) {
    const int s  = wid * 4 + si;
    const int m0 = s_m0[s];
    const float4* w1p = (const float4*)(W1_0 + (size_t)m0 * (K_TOP * H_DIM));
    float4 w1a[8], w1b[8];
#pragma unroll
    for (int k = 0; k < 8; ++k) {
      w1a[k] = w1p[k * 32 + 2 * g];
      w1b[k] = w1p[k * 32 + 2 * g + 1];
    }
    const float4 b1a = ((const float4*)(b1_0 + m0 * H_DIM))[2 * g];
    const float4 b1b = ((const float4*)(b1_0 + m0 * H_DIM))[2 * g + 1];
    const float4 w2a = ((const float4*)(W2_0 + m0 * H_DIM))[2 * g];
    const float4 w2b = ((const float4*)(W2_0 + m0 * H_DIM))[2 * g + 1];
    const float  b2v = b2_0[m0];
    int cols[8];
#pragma unroll
    for (int k = 0; k < 8; ++k) cols[k] = s_cols[s * 8 + k];

#pragma unroll
    for (int it = 0; it < 4; ++it) {
      const int r = it * 4 + rq;
      const float* xrow = xt + r * XP;
      float xv[8];
#pragma unroll
      for (int k = 0; k < 8; ++k) xv[k] = xrow[cols[k]];
      const float p = slice8(w1a, w1b, b1a, b1b, w2a, w2b, xv);
      if (g == 0) tile[s * 18 + r] = p + b2v;
    }
  }
  __syncthreads();

  // ---- layer 1: wave w -> module j=w&1, row-half w>>1; + sigmoid ----
  {
    const int j  = wid & 1;
    const int rh = wid >> 1;
    const int m1 = s_m1[j];
    const float4* w1p = (const float4*)(W1_1 + (size_t)m1 * (K_TOP * H_DIM));
    float4 w1a[8], w1b[8];
#pragma unroll
    for (int k = 0; k < 8; ++k) {
      w1a[k] = w1p[k * 32 + 2 * g];
      w1b[k] = w1p[k * 32 + 2 * g + 1];
    }
    const float4 b1a = ((const float4*)(b1_1 + m1 * H_DIM))[2 * g];
    const float4 b1b = ((const float4*)(b1_1 + m1 * H_DIM))[2 * g + 1];
    const float4 w2a = ((const float4*)(W2_1 + m1 * H_DIM))[2 * g];
    const float4 w2b = ((const float4*)(W2_1 + m1 * H_DIM))[2 * g + 1];
    const float  b2v = b2_1[m1];

#pragma unroll
    for (int it = 0; it < 2; ++it) {
      const int r = rh * 8 + it * 4 + rq;
      float xv[8];
#pragma unroll
      for (int k = 0; k < 8; ++k) xv[k] = tile[(j * 8 + k) * 18 + r];
      const float p = slice8(w1a, w1b, b1a, b1b, w2a, w2b, xv);
      if (g == 0) {
        const float v = p + b2v;
        out[(size_t)(rowbase + r) * 2 + j] = 1.f / (1.f + __expf(-v));
      }
    }
  }
}

// ---------------------------------------------------------------------------
extern "C" void kernel_launch(void* const* d_in, const int* in_sizes, int n_in,
                              void* d_out, int out_size, void* d_ws, size_t ws_size,
                              hipStream_t stream) {
  const float* x       = (const float*)d_in[0];
  const int*   task_id = (const int*)  d_in[1];
  const float* emb0    = (const float*)d_in[2];
  const float* emb1    = (const float*)d_in[3];
  const float* emb_out = (const float*)d_in[4];
  const float* W1_0    = (const float*)d_in[5];
  const float* b1_0    = (const float*)d_in[6];
  const float* W2_0    = (const float*)d_in[7];
  const float* b2_0    = (const float*)d_in[8];
  const float* W1_1    = (const float*)d_in[9];
  const float* b1_1    = (const float*)d_in[10];
  const float* W2_1    = (const float*)d_in[11];
  const float* b2_1    = (const float*)d_in[12];

  int* ws = (int*)d_ws;

  route_pre<<<dim3(32, 2), 256, 0, stream>>>(task_id, emb0, emb1, emb_out, ws);
  fused_compute<<<B_SZ / ROWS, 256, 0, stream>>>(x, W1_0, b1_0, W2_0, b2_0,
                                                 W1_1, b1_1, W2_1, b2_1,
                                                 ws, (float*)d_out);
}